// Round 7
// baseline (1183.744 us; speedup 1.0000x reference)
//
#include <hip/hip_runtime.h>
#include <math.h>

#define B_    32768
#define LN10_ 2.302585092994046f
#define MT_H  264   // padded m-tile count for sorted head GEMMs (>= 258 worst case)
#define NBLK  128   // B_/256 sort blocks

typedef __attribute__((ext_vector_type(8))) short short8;
typedef __attribute__((ext_vector_type(4))) float f32x4;

typedef const __attribute__((address_space(1))) void gvoid_t;
typedef __attribute__((address_space(3))) void svoid_t;

__device__ __forceinline__ void gl16(const void* g, void* l) {
  __builtin_amdgcn_global_load_lds((gvoid_t*)g, (svoid_t*)l, 16, 0, 0);
}

__device__ __forceinline__ float bf2f(unsigned int u) {
  union { unsigned int i; float f; } v; v.i = u << 16; return v.f;
}
// round-to-nearest-even f32 -> bf16 (finite inputs)
__device__ __forceinline__ unsigned short f2bf(float f) {
  union { float f; unsigned int i; } v; v.f = f;
  unsigned int x = v.i;
  unsigned int r = x + 0x7FFFu + ((x >> 16) & 1u);
  return (unsigned short)(r >> 16);
}

// ================= big-GEMM: 256x256 tile, K-64 tiles, 4-phase counted-vmcnt =================
// EXACT R3/R6 body (reproduced twice: e2/s2 ~145-149us, total-best config). Used for e1/s1.
// See R6 comments for schedule/WAR proofs. Requires M%256==0,N%256==0,K%64==0,gridDim.y%8==0.
#define HLF 8192  // shorts per 16KB half-tile

__global__ __launch_bounds__(512)
void gemm256(const unsigned short* __restrict__ A0_, int lda,
             const unsigned short* __restrict__ W0_, int ldw,
             unsigned short* __restrict__ C0, int ldc, int K,
             float* __restrict__ st, int Ntot) {
  __shared__ __align__(16) unsigned short lds[65536];  // 128 KiB
  const int t = threadIdx.x;
  const int nx = gridDim.x, ny = gridDim.y;
  const int f = blockIdx.y * nx + blockIdx.x;
  const int xcd = f & 7, g = f >> 3;
  const int gdiv = g / nx;
  const int mt = xcd * (ny >> 3) + gdiv;   // XCD-contiguous m-tiles (bijective: total%8==0)
  const int nt = g - gdiv * nx;
  const int mBase = mt * 256, nBase = nt * 256;
  const unsigned short* Ap = A0_ + (size_t)mBase * lda;
  const unsigned short* Wp = W0_ + (size_t)nBase * ldw;
  const int w = t >> 6, l = t & 63;
  const int wr = w >> 2, wc = w & 3;       // 2M x 4N waves; per-wave 128 rows x (32+32) cols
  const int lm = l & 15, lg = l >> 4;

  const int rr = t >> 3;                       // row within 64-row group
  const int xc = ((t & 7) ^ (rr & 7)) << 3;    // swizzled source chunk, in elements
  const unsigned short* gA = Ap + (size_t)rr * lda + xc;
  const unsigned short* gB = Wp + (size_t)rr * ldw + xc;

#define SG(ptr, ld, rowoff, dst) \
    gl16((ptr) + (size_t)(rowoff) * (ld) + ko_, &lds[(dst) + t * 8])
#define STAGE_A0(tt) { const int d_=((tt)&1)<<15; const size_t ko_=(size_t)(tt)*64; \
    SG(gA,lda,0,d_);          SG(gA,lda,64,d_+4096); }
#define STAGE_A1(tt) { const int d_=((tt)&1)<<15; const size_t ko_=(size_t)(tt)*64; \
    SG(gA,lda,128,d_+8192);   SG(gA,lda,192,d_+12288); }
#define STAGE_B0(tt) { const int d_=((tt)&1)<<15; const size_t ko_=(size_t)(tt)*64; \
    SG(gB,ldw,0,d_+16384);    SG(gB,ldw,64,d_+20480); }
#define STAGE_B1(tt) { const int d_=((tt)&1)<<15; const size_t ko_=(size_t)(tt)*64; \
    SG(gB,ldw,128,d_+24576);  SG(gB,ldw,192,d_+28672); }

  const int cs0 = ((lg) ^ (l & 7)) << 3;
  const int cs1 = ((4 | lg) ^ (l & 7)) << 3;

  f32x4 acc[8][4];
#pragma unroll
  for (int i = 0; i < 8; ++i)
#pragma unroll
    for (int j = 0; j < 4; ++j) {
      f32x4 z4 = {0.f, 0.f, 0.f, 0.f};
      acc[i][j] = z4;
    }

  const int NT = K >> 6;
  STAGE_A0(0); STAGE_A1(0); STAGE_B0(0); STAGE_B1(0);
  asm volatile("s_waitcnt vmcnt(2)" ::: "memory");  // A0,A1,B0 landed; B1 in flight
  __builtin_amdgcn_s_barrier();

  short8 af[8], bq[4];
  for (int tt = 0; tt < NT; ++tt) {
    const int d = (tt & 1) << 15;
    const bool more = (tt + 1 < NT);
    const int abase = d + wr * HLF + lm * 64;
    const int bbase = d + 2 * HLF + (wc * 32 + lm) * 64;
    // ---- q0: (kh0, j01) ----
#pragma unroll
    for (int i = 0; i < 8; ++i) af[i] = *(const short8*)&lds[abase + i * 1024 + cs0];
    bq[0] = *(const short8*)&lds[bbase + cs0];
    bq[1] = *(const short8*)&lds[bbase + 1024 + cs0];
    if (more) {
      STAGE_A0(tt + 1);
      asm volatile("s_waitcnt vmcnt(2)" ::: "memory");  // B1(tt) landed; A0(tt+1) in flight
    } else {
      asm volatile("s_waitcnt vmcnt(0)" ::: "memory");  // tail: drain B1(tt)
    }
    __builtin_amdgcn_s_barrier();
    asm volatile("s_waitcnt lgkmcnt(0)" ::: "memory");
    __builtin_amdgcn_sched_barrier(0);
    __builtin_amdgcn_s_setprio(1);
#pragma unroll
    for (int i = 0; i < 8; ++i) {
      acc[i][0] = __builtin_amdgcn_mfma_f32_16x16x32_bf16(af[i], bq[0], acc[i][0], 0, 0, 0);
      acc[i][1] = __builtin_amdgcn_mfma_f32_16x16x32_bf16(af[i], bq[1], acc[i][1], 0, 0, 0);
    }
    __builtin_amdgcn_s_setprio(0);
    __builtin_amdgcn_s_barrier();
    // ---- q1: (kh0, j23) ----
    bq[2] = *(const short8*)&lds[bbase + HLF + cs0];
    bq[3] = *(const short8*)&lds[bbase + HLF + 1024 + cs0];
    if (more) STAGE_A1(tt + 1);
    __builtin_amdgcn_s_barrier();
    asm volatile("s_waitcnt lgkmcnt(0)" ::: "memory");
    __builtin_amdgcn_sched_barrier(0);
    __builtin_amdgcn_s_setprio(1);
#pragma unroll
    for (int i = 0; i < 8; ++i) {
      acc[i][2] = __builtin_amdgcn_mfma_f32_16x16x32_bf16(af[i], bq[2], acc[i][2], 0, 0, 0);
      acc[i][3] = __builtin_amdgcn_mfma_f32_16x16x32_bf16(af[i], bq[3], acc[i][3], 0, 0, 0);
    }
    __builtin_amdgcn_s_setprio(0);
    __builtin_amdgcn_s_barrier();
    // ---- q2: (kh1, j01) ----
#pragma unroll
    for (int i = 0; i < 8; ++i) af[i] = *(const short8*)&lds[abase + i * 1024 + cs1];
    bq[0] = *(const short8*)&lds[bbase + cs1];
    bq[1] = *(const short8*)&lds[bbase + 1024 + cs1];
    if (more) STAGE_B0(tt + 1);
    __builtin_amdgcn_s_barrier();
    asm volatile("s_waitcnt lgkmcnt(0)" ::: "memory");
    __builtin_amdgcn_sched_barrier(0);
    __builtin_amdgcn_s_setprio(1);
#pragma unroll
    for (int i = 0; i < 8; ++i) {
      acc[i][0] = __builtin_amdgcn_mfma_f32_16x16x32_bf16(af[i], bq[0], acc[i][0], 0, 0, 0);
      acc[i][1] = __builtin_amdgcn_mfma_f32_16x16x32_bf16(af[i], bq[1], acc[i][1], 0, 0, 0);
    }
    __builtin_amdgcn_s_setprio(0);
    __builtin_amdgcn_s_barrier();
    // ---- q3: (kh1, j23) ----
    bq[2] = *(const short8*)&lds[bbase + HLF + cs1];
    bq[3] = *(const short8*)&lds[bbase + HLF + 1024 + cs1];
    if (more) {
      STAGE_B1(tt + 1);
      asm volatile("s_waitcnt vmcnt(2)" ::: "memory");  // A0,A1,B0(tt+1) landed; B1(tt+1) in flight
    }
    __builtin_amdgcn_s_barrier();
    asm volatile("s_waitcnt lgkmcnt(0)" ::: "memory");
    __builtin_amdgcn_sched_barrier(0);
    __builtin_amdgcn_s_setprio(1);
#pragma unroll
    for (int i = 0; i < 8; ++i) {
      acc[i][2] = __builtin_amdgcn_mfma_f32_16x16x32_bf16(af[i], bq[2], acc[i][2], 0, 0, 0);
      acc[i][3] = __builtin_amdgcn_mfma_f32_16x16x32_bf16(af[i], bq[3], acc[i][3], 0, 0, 0);
    }
    __builtin_amdgcn_s_setprio(0);
    __builtin_amdgcn_s_barrier();
  }

  // epilogue: D row = (lane>>4)*4 + reg, col = lane&15; fused col sum/sumsq
#pragma unroll
  for (int j = 0; j < 4; ++j) {
    int n = nBase + (j >> 1) * 128 + wc * 32 + (j & 1) * 16 + lm;
    float s1 = 0.f, q1 = 0.f;
#pragma unroll
    for (int i = 0; i < 8; ++i) {
      int m0 = mBase + wr * 128 + i * 16 + lg * 4;
#pragma unroll
      for (int r = 0; r < 4; ++r) {
        float v = acc[i][j][r];
        s1 += v; q1 += v * v;
        C0[(size_t)(m0 + r) * ldc + n] = f2bf(v);
      }
    }
    s1 += __shfl_xor(s1, 16, 64); s1 += __shfl_xor(s1, 32, 64);
    q1 += __shfl_xor(q1, 16, 64); q1 += __shfl_xor(q1, 32, 64);
    if (lg == 0) { atomicAdd(&st[n], s1); atomicAdd(&st[Ntot + n], q1); }
  }
}
#undef SG
#undef STAGE_A0
#undef STAGE_A1
#undef STAGE_B0
#undef STAGE_B1

// ============ gemm256f: 256x256 tile, FUSED A-side BN+ELU (consumer fusion) ============
// C = elu(bn(Araw)) @ W^T with per-column affine coef[] (a at [0,K), b at [K,2K))
// precomputed by bn_coef from the producer GEMM's fused stats. Replaces a whole
// bn_apply streaming pass (saves 268 MB HBM round-trip per use). Math chain is
// bit-identical to bn_apply: raw-bf16 -> f32 affine -> ELU -> f2bf.
// A path: global->reg (4x dwordx4) -> BN+ELU -> swizzled ds_write_b128 (both-sides
// swizzle rule #21: write applies same XOR the fragment reads expect).
// B path: gl16 pre-swizzled source (proven). Schedule: R2 2-phase (best for K=2048),
// ONE barrier per tile; loads for tile t+1 issued under tile t's MFMA (T14), drain
// vmcnt(0) at tile top covers loads issued a full tile (~2000cy) earlier.
// WAR (ring-2, one barrier/tile): tile t's ds_writes/gl16s into buf[t&1] occur after
// mid-barrier(t-1), by which ALL waves finished their tile t-2 reads of buf[t&1]
// (reads of tile t-2 precede each wave's mid-barrier(t-1) in program order). RAW:
// own loads drained by vmcnt(0); own ds_writes by lgkmcnt(0); cross-wave by barrier.
__global__ __launch_bounds__(512)
void gemm256f(const unsigned short* __restrict__ A0_, int lda,
              const unsigned short* __restrict__ W0_, int ldw,
              unsigned short* __restrict__ C0, int ldc, int K,
              float* __restrict__ stOut, int Ntot,
              const float* __restrict__ coef) {
  __shared__ __align__(16) unsigned short lds[65536];  // 128 KiB: buf[d]: A@0, B@16384
  const int t = threadIdx.x;
  const int nx = gridDim.x, ny = gridDim.y;
  const int f = blockIdx.y * nx + blockIdx.x;
  const int xcd = f & 7, g = f >> 3;
  const int gdiv = g / nx;
  const int mt = xcd * (ny >> 3) + gdiv;
  const int nt = g - gdiv * nx;
  const int mBase = mt * 256, nBase = nt * 256;
  const unsigned short* Ap = A0_ + (size_t)mBase * lda;
  const unsigned short* Wp = W0_ + (size_t)nBase * ldw;
  const int w = t >> 6, l = t & 63;
  const int wr = w >> 2, wc = w & 3;       // per-wave 128 rows x 64 cols (R2 mapping)
  const int lm = l & 15, lg = l >> 4;

  const int rr = t >> 3;                   // row within 64-row group (0..63)
  const int c8 = (t & 7) << 3;             // linear col offset (elements) for A reg-loads
  const int swz = ((t & 7) ^ (rr & 7)) << 3;  // swizzled chunk for A ds_write / B source
  const unsigned short* gAf = Ap + (size_t)rr * lda + c8;         // A: LINEAR source
  const unsigned short* gB  = Wp + (size_t)rr * ldw + swz;        // B: pre-swizzled source

#define FSTAGE_B(tt) { const int d_=((tt)&1)<<15; const size_t ko_=(size_t)(tt)*64; \
    gl16(gB + ko_,                     &lds[d_ + 16384 + t * 8]);  \
    gl16(gB + (size_t)64  * ldw + ko_, &lds[d_ + 20480 + t * 8]);  \
    gl16(gB + (size_t)128 * ldw + ko_, &lds[d_ + 24576 + t * 8]);  \
    gl16(gB + (size_t)192 * ldw + ko_, &lds[d_ + 28672 + t * 8]); }

  uint4 ar0, ar1, ar2, ar3;
  float4 caLo, caHi, cbLo, cbHi;
#define FLOADA(tt) { const size_t ko_ = (size_t)(tt) * 64; const int cb_ = (tt) * 64 + c8; \
    ar0 = *(const uint4*)&gAf[ko_];                        \
    ar1 = *(const uint4*)&gAf[(size_t)64  * lda + ko_];    \
    ar2 = *(const uint4*)&gAf[(size_t)128 * lda + ko_];    \
    ar3 = *(const uint4*)&gAf[(size_t)192 * lda + ko_];    \
    caLo = *(const float4*)&coef[cb_];     caHi = *(const float4*)&coef[cb_ + 4];     \
    cbLo = *(const float4*)&coef[K + cb_]; cbHi = *(const float4*)&coef[K + cb_ + 4]; }

  const int cs0 = ((lg) ^ (l & 7)) << 3;
  const int cs1 = ((4 | lg) ^ (l & 7)) << 3;

  f32x4 acc[8][4];
#pragma unroll
  for (int i = 0; i < 8; ++i)
#pragma unroll
    for (int j = 0; j < 4; ++j) {
      f32x4 z4 = {0.f, 0.f, 0.f, 0.f};
      acc[i][j] = z4;
    }

  const int NT = K >> 6;
  FLOADA(0); FSTAGE_B(0);

  for (int tt = 0; tt < NT; ++tt) {
    const int d = (tt & 1) << 15;
    asm volatile("s_waitcnt vmcnt(0)" ::: "memory");  // A-regs+coef+B-gl16 of tile tt landed
    __builtin_amdgcn_sched_barrier(0);
    // BN+ELU A(tt) in-register, swizzled ds_write into buf[tt&1]
    {
      float a8[8] = {caLo.x, caLo.y, caLo.z, caLo.w, caHi.x, caHi.y, caHi.z, caHi.w};
      float b8[8] = {cbLo.x, cbLo.y, cbLo.z, cbLo.w, cbHi.x, cbHi.y, cbHi.z, cbHi.w};
      uint4 uregs[4] = {ar0, ar1, ar2, ar3};
#pragma unroll
      for (int r2 = 0; r2 < 4; ++r2) {
        unsigned int uu[4] = {uregs[r2].x, uregs[r2].y, uregs[r2].z, uregs[r2].w};
        unsigned int oo[4];
#pragma unroll
        for (int k2 = 0; k2 < 4; ++k2) {
          float vlo = bf2f(uu[k2] & 0xFFFFu);
          float vhi = bf2f(uu[k2] >> 16);
          float flo = a8[2 * k2] * vlo + b8[2 * k2];
          float fhi = a8[2 * k2 + 1] * vhi + b8[2 * k2 + 1];
          flo = flo > 0.f ? flo : expm1f(flo);
          fhi = fhi > 0.f ? fhi : expm1f(fhi);
          oo[k2] = (unsigned int)f2bf(flo) | ((unsigned int)f2bf(fhi) << 16);
        }
        uint4 ov = {oo[0], oo[1], oo[2], oo[3]};
        *(uint4*)&lds[d + ((r2 * 64 + rr) << 6) + swz] = ov;
      }
    }
    const bool more = (tt + 1 < NT);
    if (more) { FLOADA(tt + 1); FSTAGE_B(tt + 1); }   // into buf[(tt+1)&1]; safe post mid-bar(tt-1)
    asm volatile("s_waitcnt lgkmcnt(0)" ::: "memory");  // own ds_writes committed
    __builtin_amdgcn_s_barrier();                       // mid-barrier: buf[tt&1] fully ready
    __builtin_amdgcn_sched_barrier(0);
    // ---- phase 0: k-half 0 ----
    {
      short8 af[8], bq[4];
#pragma unroll
      for (int i = 0; i < 8; ++i) {
        int arow = wr * 128 + i * 16 + lm;
        af[i] = *(const short8*)&lds[d + arow * 64 + cs0];
      }
#pragma unroll
      for (int j = 0; j < 4; ++j) {
        int brow = wc * 64 + j * 16 + lm;
        bq[j] = *(const short8*)&lds[d + 16384 + brow * 64 + cs0];
      }
      __builtin_amdgcn_s_setprio(1);
#pragma unroll
      for (int i = 0; i < 8; ++i)
#pragma unroll
        for (int j = 0; j < 4; ++j)
          acc[i][j] = __builtin_amdgcn_mfma_f32_16x16x32_bf16(af[i], bq[j], acc[i][j], 0, 0, 0);
      __builtin_amdgcn_s_setprio(0);
    }
    // ---- phase 1: k-half 1 ----
    {
      short8 af[8], bq[4];
#pragma unroll
      for (int i = 0; i < 8; ++i) {
        int arow = wr * 128 + i * 16 + lm;
        af[i] = *(const short8*)&lds[d + arow * 64 + cs1];
      }
#pragma unroll
      for (int j = 0; j < 4; ++j) {
        int brow = wc * 64 + j * 16 + lm;
        bq[j] = *(const short8*)&lds[d + 16384 + brow * 64 + cs1];
      }
      __builtin_amdgcn_s_setprio(1);
#pragma unroll
      for (int i = 0; i < 8; ++i)
#pragma unroll
        for (int j = 0; j < 4; ++j)
          acc[i][j] = __builtin_amdgcn_mfma_f32_16x16x32_bf16(af[i], bq[j], acc[i][j], 0, 0, 0);
      __builtin_amdgcn_s_setprio(0);
    }
  }

  // epilogue (R2 col mapping): n = nBase + wc*64 + j*16 + lm; fused col sum/sumsq
#pragma unroll
  for (int j = 0; j < 4; ++j) {
    int n = nBase + wc * 64 + j * 16 + lm;
    float s1 = 0.f, q1 = 0.f;
#pragma unroll
    for (int i = 0; i < 8; ++i) {
      int m0 = mBase + wr * 128 + i * 16 + lg * 4;
#pragma unroll
      for (int r = 0; r < 4; ++r) {
        float v = acc[i][j][r];
        s1 += v; q1 += v * v;
        C0[(size_t)(m0 + r) * ldc + n] = f2bf(v);
      }
    }
    s1 += __shfl_xor(s1, 16, 64); s1 += __shfl_xor(s1, 32, 64);
    q1 += __shfl_xor(q1, 16, 64); q1 += __shfl_xor(q1, 32, 64);
    if (lg == 0) { atomicAdd(&stOut[n], s1); atomicAdd(&stOut[Ntot + n], q1); }
  }
}
#undef FSTAGE_B
#undef FLOADA

// ---------------- BN coefficient precompute: coef[c]=a, coef[N+c]=b ----------------
__global__ void bn_coef(const float* __restrict__ st, const float* __restrict__ gam,
                        const float* __restrict__ bet, float* __restrict__ coef,
                        int N, float invB) {
  int c = blockIdx.x * 256 + threadIdx.x;
  float m = st[c] * invB;
  float var = st[N + c] * invB - m * m;
  float av = gam[c] * rsqrtf(var + 1e-5f);
  coef[c] = av;
  coef[N + c] = bet[c] - m * av;
}

// ---------------- GEMM (128x128, m97-structure): e3 + expert heads ----------------
__global__ __launch_bounds__(256)
void gemm_bt(const unsigned short* __restrict__ A0, int lda,
             const unsigned short* __restrict__ W0, int ldw,
             unsigned short* __restrict__ C0, int ldc,
             int K, const float* __restrict__ bias0, int elu,
             float* __restrict__ st, int Ntot,
             long eA, long eW, long eC, int eBias,
             const int* __restrict__ texp) {
  __shared__ __align__(16) unsigned short lA[128 * 64];
  __shared__ __align__(16) unsigned short lB[128 * 64];
  const int t = threadIdx.x;
  const int nx = gridDim.x, ny = gridDim.y;
  const int f = blockIdx.y * nx + blockIdx.x;
  const int xcd = f & 7, g = f >> 3;
  const int gdiv = g / nx;
  const int mt = xcd * (ny >> 3) + gdiv;
  const int nt = g - gdiv * nx;
  const int mBase = mt * 128;
  const int nBase = nt * 128;
  int e = texp ? texp[mt] : (int)blockIdx.z;
  if (e < 0) return;  // pad tile, uniform exit
  const unsigned short* A = A0 + (size_t)e * eA;
  const unsigned short* W = W0 + (size_t)e * eW;
  unsigned short* C = C0 + (size_t)e * eC;
  const float* bias = bias0 ? (bias0 + (size_t)e * eBias) : nullptr;
  const unsigned short* Ap = A + (size_t)mBase * lda;
  const unsigned short* Wp = W + (size_t)nBase * ldw;
  const int w = t >> 6, l = t & 63;
  const int wr = (w >> 1) * 64, wc = (w & 1) * 64;
  const int lm = l & 15, lg = l >> 4;

  f32x4 acc[4][4];
#pragma unroll
  for (int i = 0; i < 4; ++i)
#pragma unroll
    for (int j = 0; j < 4; ++j) {
      f32x4 z4 = {0.f, 0.f, 0.f, 0.f};
      acc[i][j] = z4;
    }

  for (int k0 = 0; k0 < K; k0 += 64) {
    __syncthreads();
#pragma unroll
    for (int it = 0; it < 4; ++it) {
      int chunk = it * 256 + t;
      int row = chunk >> 3, sc = chunk & 7;
      int gc = (sc ^ (row & 7)) << 3;  // swizzled source chunk (element offset)
      gl16(Ap + (size_t)row * lda + k0 + gc, &lA[chunk * 8]);
      gl16(Wp + (size_t)row * ldw + k0 + gc, &lB[chunk * 8]);
    }
    __syncthreads();
#pragma unroll
    for (int kk = 0; kk < 64; kk += 32) {
      short8 af[4], bfr[4];
#pragma unroll
      for (int i = 0; i < 4; ++i) {
        int ar = wr + i * 16 + lm;
        int ac = (kk >> 3) + lg;
        af[i] = *(const short8*)&lA[ar * 64 + ((ac ^ (ar & 7)) << 3)];
      }
#pragma unroll
      for (int j = 0; j < 4; ++j) {
        int br = wc + j * 16 + lm;
        int bc = (kk >> 3) + lg;
        bfr[j] = *(const short8*)&lB[br * 64 + ((bc ^ (br & 7)) << 3)];
      }
#pragma unroll
      for (int i = 0; i < 4; ++i)
#pragma unroll
        for (int j = 0; j < 4; ++j)
          acc[i][j] = __builtin_amdgcn_mfma_f32_16x16x32_bf16(af[i], bfr[j], acc[i][j], 0, 0, 0);
    }
  }

  // epilogue: D row = (lane>>4)*4 + reg, col = lane&15
#pragma unroll
  for (int j = 0; j < 4; ++j) {
    int n = nBase + wc + j * 16 + lm;
    float bj = bias ? bias[n] : 0.f;
    float s = 0.f, q = 0.f;
#pragma unroll
    for (int i = 0; i < 4; ++i) {
      int m0 = mBase + wr + i * 16 + lg * 4;
#pragma unroll
      for (int r = 0; r < 4; ++r) {
        float v = acc[i][j][r] + bj;
        if (elu) v = v > 0.f ? v : expm1f(v);
        s += v; q += v * v;
        C[(size_t)(m0 + r) * ldc + n] = f2bf(v);
      }
    }
    if (st) {
      s += __shfl_xor(s, 16, 64); s += __shfl_xor(s, 32, 64);
      q += __shfl_xor(q, 16, 64); q += __shfl_xor(q, 32, 64);
      if (lg == 0) { atomicAdd(&st[n], s); atomicAdd(&st[Ntot + n], q); }
    }
  }
}

// ---------------- in-place BN + ELU on bf16 [B,N], 8 elems/thread (N pow2)
__global__ void bn_apply(unsigned short* __restrict__ Y, const float* __restrict__ st,
                         const float* __restrict__ gam, const float* __restrict__ bet,
                         int N, float invB) {
  size_t i = (size_t)blockIdx.x * blockDim.x + threadIdx.x;
  size_t base = i * 8;
  int col = (int)(base & (size_t)(N - 1));
  float a8[8], b8[8];
#pragma unroll
  for (int k = 0; k < 8; ++k) {
    int c = col + k;
    float m = st[c] * invB;
    float var = st[N + c] * invB - m * m;
    float av = gam[c] * rsqrtf(var + 1e-5f);
    a8[k] = av;
    b8[k] = bet[c] - m * av;
  }
  uint4 u = *(uint4*)&Y[base];
  unsigned int uu[4] = {u.x, u.y, u.z, u.w};
  unsigned int oo[4];
#pragma unroll
  for (int k = 0; k < 4; ++k) {
    float vlo = bf2f(uu[k] & 0xFFFFu);
    float vhi = bf2f(uu[k] >> 16);
    float flo = a8[2 * k] * vlo + b8[2 * k];
    float fhi = a8[2 * k + 1] * vhi + b8[2 * k + 1];
    flo = flo > 0.f ? flo : expm1f(flo);
    fhi = fhi > 0.f ? fhi : expm1f(fhi);
    oo[k] = (unsigned int)f2bf(flo) | ((unsigned int)f2bf(fhi) << 16);
  }
  uint4 o = {oo[0], oo[1], oo[2], oo[3]};
  *(uint4*)&Y[base] = o;
}

// ---------------- cast ALL weights fp32->bf16 in one launch
__global__ void cast_all(const float* __restrict__ e1, const float* __restrict__ e2,
                         const float* __restrict__ e3, const float* __restrict__ s1,
                         const float* __restrict__ s2, const float* __restrict__ h1,
                         const float* __restrict__ h2, unsigned short* __restrict__ dst) {
  int i4 = blockIdx.x * 256 + threadIdx.x;
  const float* src;
  int rel;
  if (i4 < 786432) {
    if (i4 < 262144) { src = e1; rel = i4; }
    else             { src = e2; rel = i4 - 262144; }
  } else if (i4 < 1146880) {
    if (i4 < 819200) { src = e3; rel = i4 - 786432; }
    else             { src = s1; rel = i4 - 819200; }
  } else if (i4 < 2064384) {
    if (i4 < 1671168) { src = s2; rel = i4 - 1146880; }
    else              { src = h1; rel = i4 - 1671168; }
  } else { src = h2; rel = i4 - 2064384; }
  float4 v = ((const float4*)src)[rel];
  ushort4 o = {f2bf(v.x), f2bf(v.y), f2bf(v.z), f2bf(v.w)};
  ((ushort4*)dst)[i4] = o;
}

// ---------------- cast x [B,512] fp32 into z[:,128:640] bf16 (ld 640)
__global__ void cast_x(const float* __restrict__ x, unsigned short* __restrict__ z) {
  int i = blockIdx.x * blockDim.x + threadIdx.x;  // over B*128
  int b = i >> 7;
  int c = (i & 127) << 2;
  float4 v = *(const float4*)&x[(size_t)b * 512 + c];
  ushort4 o = {f2bf(v.x), f2bf(v.y), f2bf(v.z), f2bf(v.w)};
  *(ushort4*)&z[(size_t)b * 640 + 128 + c] = o;
}

// ---------------- sort step 1: per-block expert counts via wave ballots (NO atomics)
__global__ void hist_blocks(const int* __restrict__ gidx, int* __restrict__ bcnt) {
  int blk = blockIdx.x;
  int i = blk * 256 + threadIdx.x;
  int e = gidx[i];
  int l = threadIdx.x & 63, w = threadIdx.x >> 6;
  __shared__ int wc[4][3];
  unsigned long long m0 = __ballot(e == 0);
  unsigned long long m1 = __ballot(e == 1);
  unsigned long long m2 = __ballot(e == 2);
  if (l == 0) { wc[w][0] = __popcll(m0); wc[w][1] = __popcll(m1); wc[w][2] = __popcll(m2); }
  __syncthreads();
  if (threadIdx.x < 3)
    bcnt[blk * 3 + threadIdx.x] = wc[0][threadIdx.x] + wc[1][threadIdx.x] +
                                  wc[2][threadIdx.x] + wc[3][threadIdx.x];
}

// ---------------- sort step 2: one block; segment starts, vend, texp, and
// per-block exclusive offsets boff[blk][e]
__global__ void scan_plan(const int* __restrict__ bcnt, int* __restrict__ boff,
                          int* __restrict__ vend, int* __restrict__ texp) {
  __shared__ int sp[4];
  __shared__ int cnt[3];
  int t = threadIdx.x;
  if (t < 3) {
    int s = 0;
    for (int b = 0; b < NBLK; ++b) s += bcnt[b * 3 + t];
    cnt[t] = s;
  }
  __syncthreads();
  if (t == 0) {
    int p = 0;
    for (int e = 0; e < 3; ++e) {
      sp[e] = p; vend[e] = p + cnt[e];
      p += ((cnt[e] + 127) >> 7) << 7;
    }
    sp[3] = p;
  }
  __syncthreads();
  if (t < 3) {
    int run = sp[t];
    for (int b = 0; b < NBLK; ++b) { boff[b * 3 + t] = run; run += bcnt[b * 3 + t]; }
  }
  if (t < MT_H) {
    int r0 = t << 7, e = -1;
    for (int k = 0; k < 3; ++k)
      if (r0 >= sp[k] && r0 < sp[k + 1]) e = k;
    texp[t] = e;
  }
}

// ---------------- sort step 3: scatter via ballot-rank (NO atomics, stable)
__global__ void scatter2(const int* __restrict__ gidx, const int* __restrict__ boff,
                         int* __restrict__ perm) {
  int blk = blockIdx.x;
  int i = blk * 256 + threadIdx.x;
  int e = gidx[i];
  int l = threadIdx.x & 63, w = threadIdx.x >> 6;
  __shared__ int wc[4][3];
  unsigned long long m0 = __ballot(e == 0);
  unsigned long long m1 = __ballot(e == 1);
  unsigned long long m2 = __ballot(e == 2);
  if (l == 0) { wc[w][0] = __popcll(m0); wc[w][1] = __popcll(m1); wc[w][2] = __popcll(m2); }
  __syncthreads();
  unsigned long long me = (e == 0) ? m0 : ((e == 1) ? m1 : m2);
  int rank = __popcll(me & ((1ull << l) - 1ull));
  int woff = 0;
  for (int ww = 0; ww < w; ++ww) woff += wc[ww][e];
  perm[boff[blk * 3 + e] + woff + rank] = i;
}

// ---------------- gather + FUSED BN+ELU (s2 output): raw hidden -> bn -> ht
__global__ void gather_bn(const unsigned short* __restrict__ hid, const int* __restrict__ perm,
                          const int* __restrict__ texp, const int* __restrict__ vend,
                          const float* __restrict__ st, const float* __restrict__ gam,
                          const float* __restrict__ bet, float invB,
                          unsigned short* __restrict__ ht) {
  int idx = blockIdx.x * 256 + threadIdx.x;  // over MT_H*128*128
  int p = idx >> 7, c8 = (idx & 127) << 3;   // 8 cols of 1024 per thread
  int e = texp[p >> 7];
  uint4 o = {0u, 0u, 0u, 0u};
  if (e >= 0 && p < vend[e]) {
    float a8[8], b8[8];
#pragma unroll
    for (int k = 0; k < 8; ++k) {
      int c = c8 + k;
      float m = st[c] * invB;
      float var = st[1024 + c] * invB - m * m;
      float av = gam[c] * rsqrtf(var + 1e-5f);
      a8[k] = av;
      b8[k] = bet[c] - m * av;
    }
    int src = perm[p];
    uint4 u = *(const uint4*)&hid[(size_t)src * 1024 + c8];
    unsigned int uu[4] = {u.x, u.y, u.z, u.w};
    unsigned int oo[4];
#pragma unroll
    for (int k = 0; k < 4; ++k) {
      float vlo = bf2f(uu[k] & 0xFFFFu);
      float vhi = bf2f(uu[k] >> 16);
      float flo = a8[2 * k] * vlo + b8[2 * k];
      float fhi = a8[2 * k + 1] * vhi + b8[2 * k + 1];
      flo = flo > 0.f ? flo : expm1f(flo);
      fhi = fhi > 0.f ? fhi : expm1f(fhi);
      oo[k] = (unsigned int)f2bf(flo) | ((unsigned int)f2bf(fhi) << 16);
    }
    o.x = oo[0]; o.y = oo[1]; o.z = oo[2]; o.w = oo[3];
  }
  *(uint4*)&ht[(size_t)p * 1024 + c8] = o;
}

// ---------------- final: per sorted row p, dot(t2p[p,:], w3[e]) + b3[e], softplus
__global__ void final_pred(const unsigned short* __restrict__ t2, const int* __restrict__ perm,
                           const int* __restrict__ texp, const int* __restrict__ vend,
                           const float* __restrict__ w3, const float* __restrict__ b3,
                           float* __restrict__ out) {
  int p = blockIdx.x * 4 + (threadIdx.x >> 6);
  int l = threadIdx.x & 63;
  int e = texp[p >> 7];
  if (e < 0 || p >= vend[e]) return;
  ushort4 u = *(const ushort4*)&t2[(size_t)p * 256 + l * 4];
  float4 wv = *(const float4*)&w3[e * 256 + l * 4];
  float sum = bf2f(u.x) * wv.x + bf2f(u.y) * wv.y + bf2f(u.z) * wv.z + bf2f(u.w) * wv.w;
#pragma unroll
  for (int off = 32; off; off >>= 1) sum += __shfl_down(sum, off, 64);
  if (l == 0) {
    int orig = perm[p];
    float xr = sum + b3[e];
    float sp = (xr > 0.f) ? (xr + log1pf(expf(-xr))) : log1pf(expf(xr));
    float pl = -sp;
    out[orig] = pl;
    out[B_ + orig] = expf(pl * LN10_);
  }
}

extern "C" void kernel_launch(void* const* d_in, const int* in_sizes, int n_in,
                              void* d_out, int out_size, void* d_ws, size_t ws_size,
                              hipStream_t stream) {
  const float* x    = (const float*)d_in[0];
  const int*   gidx = (const int*)d_in[1];
  const float* e_w1 = (const float*)d_in[2];
  const float* e_g1 = (const float*)d_in[4];
  const float* e_be1= (const float*)d_in[5];
  const float* e_w2 = (const float*)d_in[6];
  const float* e_g2 = (const float*)d_in[8];
  const float* e_be2= (const float*)d_in[9];
  const float* e_w3 = (const float*)d_in[10];
  const float* e_b3 = (const float*)d_in[11];
  const float* s_w1 = (const float*)d_in[12];
  const float* s_g1 = (const float*)d_in[14];
  const float* s_be1= (const float*)d_in[15];
  const float* s_w2 = (const float*)d_in[16];
  const float* s_g2 = (const float*)d_in[18];
  const float* s_be2= (const float*)d_in[19];
  const float* h_w1 = (const float*)d_in[20];
  const float* h_b1 = (const float*)d_in[21];
  const float* h_w2 = (const float*)d_in[22];
  const float* h_b2 = (const float*)d_in[23];
  const float* h_w3 = (const float*)d_in[24];
  const float* h_b3 = (const float*)d_in[25];
  float* out = (float*)d_out;

  char* ws = (char*)d_ws;
  size_t off = 0;
  auto alloc = [&](size_t bytes) -> char* {
    char* p = ws + off;
    off += (bytes + 255) & ~(size_t)255;
    return p;
  };
  // bf16 weight buffers MUST stay contiguous & in this order (cast_all table)
  unsigned short* wb_e1 = (unsigned short*)alloc((size_t)2048 * 512 * 2);
  unsigned short* wb_e2 = (unsigned short*)alloc((size_t)1024 * 2048 * 2);
  unsigned short* wb_e3 = (unsigned short*)alloc((size_t)128 * 1024 * 2);
  unsigned short* wb_s1 = (unsigned short*)alloc((size_t)2048 * 640 * 2);
  unsigned short* wb_s2 = (unsigned short*)alloc((size_t)1024 * 2048 * 2);
  unsigned short* wb_h1 = (unsigned short*)alloc((size_t)3 * 512 * 1024 * 2);
  unsigned short* wb_h2 = (unsigned short*)alloc((size_t)3 * 256 * 512 * 2);
  unsigned short* z     = (unsigned short*)alloc((size_t)B_ * 640 * 2);
  unsigned short* bufA  = (unsigned short*)alloc((size_t)B_ * 2048 * 2);
  unsigned short* bufB  = (unsigned short*)alloc((size_t)B_ * 1024 * 2);
  // BN stats (memset each call)
  float* st = (float*)alloc(12288 * sizeof(float));
  float* st0 = st;            // e1: 2*2048
  float* st1 = st + 4096;     // e2: 2*1024
  float* st2 = st + 6144;     // s1: 2*2048
  float* st3 = st + 10240;    // s2: 2*1024
  float* coefbuf = (float*)alloc(4096 * sizeof(float));  // a[0:2048], b[2048:4096]
  // sort plan (all written before read each call; no memset needed)
  int* bcnt = (int*)alloc(NBLK * 3 * sizeof(int));
  int* boff = (int*)alloc(NBLK * 3 * sizeof(int));
  int* vend = (int*)alloc(3 * sizeof(int));
  int* texp = (int*)alloc(MT_H * sizeof(int));
  int* perm = (int*)alloc((size_t)MT_H * 128 * sizeof(int));
  // head buffers carved from dead regions:
  unsigned short* ht  = bufA;                                    // [MT_H*128,1024]
  unsigned short* t1p = bufA + (size_t)MT_H * 128 * 1024;        // [MT_H*128, 512]
  unsigned short* t2p = z;                                       // [MT_H*128, 256] (z dead then)

  cast_all<<<8448, 256, 0, stream>>>(e_w1, e_w2, e_w3, s_w1, s_w2, h_w1, h_w2, wb_e1);
  cast_x<<<(B_ * 128) / 256, 256, 0, stream>>>(x, z);
  hipMemsetAsync(st, 0, 12288 * sizeof(float), stream);
  // expert sort plan — deterministic, atomic-free
  hist_blocks<<<NBLK, 256, 0, stream>>>(gidx, bcnt);
  scan_plan<<<1, 512, 0, stream>>>(bcnt, boff, vend, texp);
  scatter2<<<NBLK, 256, 0, stream>>>(gidx, boff, perm);

  // encoder L1: [B,512] x [2048,512]^T -> bufA RAW (+st0)
  gemm256<<<dim3(8, 128), 512, 0, stream>>>(z + 128, 640, wb_e1, 512, bufA, 2048, 512,
                                            st0, 2048);
  // BN(e1) coefficients from st0; BN+ELU applied inside e2's A-staging (no bn_apply pass)
  bn_coef<<<8, 256, 0, stream>>>(st0, e_g1, e_be1, coefbuf, 2048, 1.0f / B_);
  // encoder L2 (FUSED A-BN): [B,2048] x [1024,2048]^T -> bufB RAW (+st1)
  gemm256f<<<dim3(4, 128), 512, 0, stream>>>(bufA, 2048, wb_e2, 2048, bufB, 1024, 2048,
                                             st1, 1024, coefbuf);
  bn_apply<<<B_ / 2, 256, 0, stream>>>(bufB, st1, e_g2, e_be2, 1024, 1.0f / B_);
  // latent: [B,1024] x [128,1024]^T -> z[:,0:128] (ldc 640), +e_b3
  gemm_bt<<<dim3(1, 256), 256, 0, stream>>>(bufB, 1024, wb_e3, 1024, z, 640, 1024,
                                            e_b3, 0, nullptr, 0, 0, 0, 0, 0, nullptr);
  // shared L1: [B,640] x [2048,640]^T -> bufA RAW (+st2)
  gemm256<<<dim3(8, 128), 512, 0, stream>>>(z, 640, wb_s1, 640, bufA, 2048, 640,
                                            st2, 2048);
  // BN(s1) coefficients; fused into s2's A-staging (coefbuf reuse safe: e2 done)
  bn_coef<<<8, 256, 0, stream>>>(st2, s_g1, s_be1, coefbuf, 2048, 1.0f / B_);
  // shared L2 (FUSED A-BN): [B,2048] x [1024,2048]^T -> bufB RAW (+st3)
  gemm256f<<<dim3(4, 128), 512, 0, stream>>>(bufA, 2048, wb_s2, 2048, bufB, 1024, 2048,
                                             st3, 1024, coefbuf);
  // NO bn_apply for s2: BN+ELU fused into gather_bn below.

  // gather RAW hidden -> BN+ELU -> expert-sorted ht (bufA dead after s2's A-read)
  gather_bn<<<(MT_H * 128 * 128) / 256, 256, 0, stream>>>(bufB, perm, texp, vend,
                                                          st3, s_g2, s_be2, 1.0f / B_, ht);

  // head L1, expert-sparse: t1p = elu(ht @ h_w1[e(mt)]^T + h_b1[e]) [Mp,512]
  gemm_bt<<<dim3(4, MT_H), 256, 0, stream>>>(ht, 1024, wb_h1, 1024, t1p, 512, 1024,
                                             h_b1, 1, nullptr, 0,
                                             0, (long)512 * 1024, 0, 512, texp);
  // head L2, expert-sparse: t2p = elu(t1p @ h_w2[e(mt)]^T + h_b2[e]) [Mp,256]
  gemm_bt<<<dim3(2, MT_H), 256, 0, stream>>>(t1p, 512, wb_h2, 512, t2p, 256, 512,
                                             h_b2, 1, nullptr, 0,
                                             0, (long)256 * 512, 0, 256, texp);

  final_pred<<<(MT_H * 128) / 4, 256, 0, stream>>>(t2p, perm, texp, vend, h_w3, h_b3, out);
}

// Round 8
// 940.101 us; speedup vs baseline: 1.2592x; 1.2592x over previous
//
#include <hip/hip_runtime.h>
#include <math.h>

#define B_    32768
#define LN10_ 2.302585092994046f
#define MT_H  264   // padded m-tile count for sorted head GEMMs (>= 258 worst case)
#define NBLK  128   // B_/256 sort blocks

typedef __attribute__((ext_vector_type(8))) short short8;
typedef __attribute__((ext_vector_type(4))) float f32x4;

typedef const __attribute__((address_space(1))) void gvoid_t;
typedef __attribute__((address_space(3))) void svoid_t;

__device__ __forceinline__ void gl16(const void* g, void* l) {
  __builtin_amdgcn_global_load_lds((gvoid_t*)g, (svoid_t*)l, 16, 0, 0);
}

__device__ __forceinline__ float bf2f(unsigned int u) {
  union { unsigned int i; float f; } v; v.i = u << 16; return v.f;
}
// round-to-nearest-even f32 -> bf16 (finite inputs)
__device__ __forceinline__ unsigned short f2bf(float f) {
  union { float f; unsigned int i; } v; v.f = f;
  unsigned int x = v.i;
  unsigned int r = x + 0x7FFFu + ((x >> 16) & 1u);
  return (unsigned short)(r >> 16);
}

// ======== big-GEMM: 256x256 tile, K-64 tiles, quadrant phases + DEEP prefetch ========
// R8: same tile/frag geometry as R6, but the pipeline is deepened to m201-style
// half-tile-granular staging. Per tile tt, 4 phases (r-half x j-half, 16 MFMA each,
// 24 ds_reads/tile min: A-frags held across j-phases, B-frags held across r-phases):
//   q0 (r0,j01): read A-r0(8)+B01(4); stage Ab(tt+1); BAR; lgkm0; MFMA
//   q1 (r0,j23): read B23(4);         stage Aa(tt+2); BAR; lgkm0; MFMA
//   q2 (r1,j01): read A-r1(8);        stage B0(tt+2); BAR; lgkm0; MFMA
//   q3 (r1,j23): stage B1(tt+2); MFMA; vmcnt(6); BAR
// ONE barrier/phase (4/tile, was 8) and ONE counted wait/tile.
// LDS regions (per dbuf d=(tt&1)<<15, shorts): A linear [row][64] rows 0..255 at
// [0,16384); B rows at [16384,32768). Stage halves regrouped to match CONSUMPTION:
//   Aa = rows 0-63 & 128-191 (the r0-rows of both waves)  -> freed after bar(q0)
//   Ab = rows 64-127 & 192-255 (r1-rows)                  -> freed after bar(q2)
//   B0 = B rows 0-127 (j01 cols)                          -> freed after bar(q0)
//   B1 = B rows 128-255 (j23 cols)                        -> freed after bar(q1)
// WAR ledger (stage -> region -> last-read phase -> covering barrier):
//   Ab(tt+1)@q0(tt) -> Abuf[(tt+1)&1] -> q2(tt-1) -> bar(q3(tt-1)) precedes q0(tt) OK
//   Aa(tt+2)@q1(tt) -> Abuf[tt&1]     -> q0(tt)   -> bar(q0(tt)) OK
//   B0(tt+2)@q2(tt) -> Bbuf[tt&1]     -> q0(tt)   -> bar(q0/q1) OK
//   B1(tt+2)@q3(tt) -> Bbuf[tt&1]     -> q1(tt)   -> bar(q1/q2) OK
//   (issuer passed the covering barrier => all waves' reads of the region issued;
//    gl16's LDS write lands >=200cy later, far after those ds_reads complete)
// RAW ledger (in-order vmcnt; each stage = 2 loads): at q3(tt) 14 loads outstanding
// [Aa,B0,B1(tt+1) issued q1-q3(tt-1); Ab(tt+1)@q0(tt); Aa,B0,B1(tt+2)@q1-q3(tt)];
// vmcnt(6) waits the 8 oldest = ALL of tile tt+1 -> barrier -> q0(tt+1) reads safe.
// Flight per half-tile: 3-6 phases (vs R6's 1) -> latency off the critical path.
// Requires: M%256==0, N%256==0, K%64==0, gridDim.y%8==0.
__global__ __launch_bounds__(512)
void gemm256(const unsigned short* __restrict__ A0_, int lda,
             const unsigned short* __restrict__ W0_, int ldw,
             unsigned short* __restrict__ C0, int ldc, int K,
             float* __restrict__ st, int Ntot) {
  __shared__ __align__(16) unsigned short lds[65536];  // 128 KiB
  const int t = threadIdx.x;
  const int nx = gridDim.x, ny = gridDim.y;
  const int f = blockIdx.y * nx + blockIdx.x;
  const int xcd = f & 7, g = f >> 3;
  const int gdiv = g / nx;
  const int mt = xcd * (ny >> 3) + gdiv;   // XCD-contiguous m-tiles (bijective: total%8==0)
  const int nt = g - gdiv * nx;
  const int mBase = mt * 256, nBase = nt * 256;
  const unsigned short* Ap = A0_ + (size_t)mBase * lda;
  const unsigned short* Wp = W0_ + (size_t)nBase * ldw;
  const int w = t >> 6, l = t & 63;
  const int wr = w >> 2, wc = w & 3;       // 2M x 4N waves; per-wave 128 rows x (32+32) cols
  const int lm = l & 15, lg = l >> 4;

  // staging source (line-coalesced, source pre-swizzled: dest chunk t&7 holds
  // source chunk (t&7)^(rr&7); reads use cs = (kc^(row&7))<<3 — involution OK)
  const int rr = t >> 3;                       // row within 64-row group
  const int xc = ((t & 7) ^ (rr & 7)) << 3;    // swizzled source chunk, in elements
  const unsigned short* gA = Ap + (size_t)rr * lda + xc;
  const unsigned short* gB = Wp + (size_t)rr * ldw + xc;

#define SG(ptr, ld, rowoff, dst) \
    gl16((ptr) + (size_t)(rowoff) * (ld) + ko_, &lds[(dst) + t * 8])
#define STAGE_Aa(tt) { const int d_=((tt)&1)<<15; const size_t ko_=(size_t)(tt)*64; \
    SG(gA,lda,0,d_);          SG(gA,lda,128,d_+8192); }
#define STAGE_Ab(tt) { const int d_=((tt)&1)<<15; const size_t ko_=(size_t)(tt)*64; \
    SG(gA,lda,64,d_+4096);    SG(gA,lda,192,d_+12288); }
#define STAGE_B0(tt) { const int d_=((tt)&1)<<15; const size_t ko_=(size_t)(tt)*64; \
    SG(gB,ldw,0,d_+16384);    SG(gB,ldw,64,d_+20480); }
#define STAGE_B1(tt) { const int d_=((tt)&1)<<15; const size_t ko_=(size_t)(tt)*64; \
    SG(gB,ldw,128,d_+24576);  SG(gB,ldw,192,d_+28672); }

  // fragment-read swizzled chunk offsets (elements), per k-half; row&7 == l&7.
  const int cs0 = ((lg) ^ (l & 7)) << 3;
  const int cs1 = ((4 | lg) ^ (l & 7)) << 3;

  f32x4 acc[8][4];
#pragma unroll
  for (int i = 0; i < 8; ++i)
#pragma unroll
    for (int j = 0; j < 4; ++j) {
      f32x4 z4 = {0.f, 0.f, 0.f, 0.f};
      acc[i][j] = z4;
    }

  const int NT = K >> 6;
  // prologue: tile 0 fully + tile 1 minus Ab (issued at q0(0)); confirm tile 0.
  STAGE_Aa(0); STAGE_B0(0); STAGE_B1(0); STAGE_Ab(0);
  if (NT > 1) {
    STAGE_Aa(1); STAGE_B0(1); STAGE_B1(1);
    asm volatile("s_waitcnt vmcnt(6)" ::: "memory");  // tile0 landed; tile1 (6) in flight
  } else {
    asm volatile("s_waitcnt vmcnt(0)" ::: "memory");
  }
  __builtin_amdgcn_s_barrier();
  __builtin_amdgcn_sched_barrier(0);

  short8 af[4][2], b01[2][2], b23[2][2];
  for (int tt = 0; tt < NT; ++tt) {
    const int d = (tt & 1) << 15;
    const int abase = d + (wr * 128 + lm) * 64;
    const int bbase = d + 16384 + (wc * 32 + lm) * 64;
    const bool s1ok = (tt + 1 < NT), s2ok = (tt + 2 < NT);
    // ---- q0: (r0, j01) ----
#pragma unroll
    for (int fi = 0; fi < 4; ++fi) {
      af[fi][0] = *(const short8*)&lds[abase + fi * 1024 + cs0];
      af[fi][1] = *(const short8*)&lds[abase + fi * 1024 + cs1];
    }
#pragma unroll
    for (int fj = 0; fj < 2; ++fj) {
      b01[fj][0] = *(const short8*)&lds[bbase + fj * 1024 + cs0];
      b01[fj][1] = *(const short8*)&lds[bbase + fj * 1024 + cs1];
    }
    if (s1ok) STAGE_Ab(tt + 1);
    __builtin_amdgcn_s_barrier();
    asm volatile("s_waitcnt lgkmcnt(0)" ::: "memory");
    __builtin_amdgcn_sched_barrier(0);
    __builtin_amdgcn_s_setprio(1);
#pragma unroll
    for (int fi = 0; fi < 4; ++fi) {
      acc[fi][0] = __builtin_amdgcn_mfma_f32_16x16x32_bf16(af[fi][0], b01[0][0], acc[fi][0], 0, 0, 0);
      acc[fi][0] = __builtin_amdgcn_mfma_f32_16x16x32_bf16(af[fi][1], b01[0][1], acc[fi][0], 0, 0, 0);
      acc[fi][1] = __builtin_amdgcn_mfma_f32_16x16x32_bf16(af[fi][0], b01[1][0], acc[fi][1], 0, 0, 0);
      acc[fi][1] = __builtin_amdgcn_mfma_f32_16x16x32_bf16(af[fi][1], b01[1][1], acc[fi][1], 0, 0, 0);
    }
    __builtin_amdgcn_s_setprio(0);
    // ---- q1: (r0, j23) ----
#pragma unroll
    for (int fj = 0; fj < 2; ++fj) {
      b23[fj][0] = *(const short8*)&lds[bbase + 8192 + fj * 1024 + cs0];
      b23[fj][1] = *(const short8*)&lds[bbase + 8192 + fj * 1024 + cs1];
    }
    if (s2ok) STAGE_Aa(tt + 2);
    __builtin_amdgcn_s_barrier();
    asm volatile("s_waitcnt lgkmcnt(0)" ::: "memory");
    __builtin_amdgcn_sched_barrier(0);
    __builtin_amdgcn_s_setprio(1);
#pragma unroll
    for (int fi = 0; fi < 4; ++fi) {
      acc[fi][2] = __builtin_amdgcn_mfma_f32_16x16x32_bf16(af[fi][0], b23[0][0], acc[fi][2], 0, 0, 0);
      acc[fi][2] = __builtin_amdgcn_mfma_f32_16x16x32_bf16(af[fi][1], b23[0][1], acc[fi][2], 0, 0, 0);
      acc[fi][3] = __builtin_amdgcn_mfma_f32_16x16x32_bf16(af[fi][0], b23[1][0], acc[fi][3], 0, 0, 0);
      acc[fi][3] = __builtin_amdgcn_mfma_f32_16x16x32_bf16(af[fi][1], b23[1][1], acc[fi][3], 0, 0, 0);
    }
    __builtin_amdgcn_s_setprio(0);
    // ---- q2: (r1, j01) ----
#pragma unroll
    for (int fi = 0; fi < 4; ++fi) {
      af[fi][0] = *(const short8*)&lds[abase + 4096 + fi * 1024 + cs0];
      af[fi][1] = *(const short8*)&lds[abase + 4096 + fi * 1024 + cs1];
    }
    if (s2ok) STAGE_B0(tt + 2);
    __builtin_amdgcn_s_barrier();
    asm volatile("s_waitcnt lgkmcnt(0)" ::: "memory");
    __builtin_amdgcn_sched_barrier(0);
    __builtin_amdgcn_s_setprio(1);
#pragma unroll
    for (int fi = 0; fi < 4; ++fi) {
      acc[4 + fi][0] = __builtin_amdgcn_mfma_f32_16x16x32_bf16(af[fi][0], b01[0][0], acc[4 + fi][0], 0, 0, 0);
      acc[4 + fi][0] = __builtin_amdgcn_mfma_f32_16x16x32_bf16(af[fi][1], b01[0][1], acc[4 + fi][0], 0, 0, 0);
      acc[4 + fi][1] = __builtin_amdgcn_mfma_f32_16x16x32_bf16(af[fi][0], b01[1][0], acc[4 + fi][1], 0, 0, 0);
      acc[4 + fi][1] = __builtin_amdgcn_mfma_f32_16x16x32_bf16(af[fi][1], b01[1][1], acc[4 + fi][1], 0, 0, 0);
    }
    __builtin_amdgcn_s_setprio(0);
    // ---- q3: (r1, j23) ---- (no new reads; MFMA first, wait hides under it)
    if (s2ok) STAGE_B1(tt + 2);
    __builtin_amdgcn_s_setprio(1);
#pragma unroll
    for (int fi = 0; fi < 4; ++fi) {
      acc[4 + fi][2] = __builtin_amdgcn_mfma_f32_16x16x32_bf16(af[fi][0], b23[0][0], acc[4 + fi][2], 0, 0, 0);
      acc[4 + fi][2] = __builtin_amdgcn_mfma_f32_16x16x32_bf16(af[fi][1], b23[0][1], acc[4 + fi][2], 0, 0, 0);
      acc[4 + fi][3] = __builtin_amdgcn_mfma_f32_16x16x32_bf16(af[fi][0], b23[1][0], acc[4 + fi][3], 0, 0, 0);
      acc[4 + fi][3] = __builtin_amdgcn_mfma_f32_16x16x32_bf16(af[fi][1], b23[1][1], acc[4 + fi][3], 0, 0, 0);
    }
    __builtin_amdgcn_s_setprio(0);
    if (s1ok) {
      if (s2ok) { asm volatile("s_waitcnt vmcnt(6)" ::: "memory"); }  // tile tt+1 landed
      else      { asm volatile("s_waitcnt vmcnt(0)" ::: "memory"); }
      __builtin_amdgcn_s_barrier();
      __builtin_amdgcn_sched_barrier(0);
    }
  }

  // epilogue: D row = (lane>>4)*4 + reg, col = lane&15; fused col sum/sumsq
  // cols: j<2 -> nBase + wc*32 + j*16; j>=2 -> nBase + 128 + wc*32 + (j-2)*16
#pragma unroll
  for (int j = 0; j < 4; ++j) {
    int n = nBase + (j >> 1) * 128 + wc * 32 + (j & 1) * 16 + lm;
    float s1 = 0.f, q1 = 0.f;
#pragma unroll
    for (int i = 0; i < 8; ++i) {
      int m0 = mBase + wr * 128 + i * 16 + lg * 4;
#pragma unroll
      for (int r = 0; r < 4; ++r) {
        float v = acc[i][j][r];
        s1 += v; q1 += v * v;
        C0[(size_t)(m0 + r) * ldc + n] = f2bf(v);
      }
    }
    s1 += __shfl_xor(s1, 16, 64); s1 += __shfl_xor(s1, 32, 64);
    q1 += __shfl_xor(q1, 16, 64); q1 += __shfl_xor(q1, 32, 64);
    if (lg == 0) { atomicAdd(&st[n], s1); atomicAdd(&st[Ntot + n], q1); }
  }
}
#undef SG
#undef STAGE_Aa
#undef STAGE_Ab
#undef STAGE_B0
#undef STAGE_B1

// ---------------- GEMM (128x128, m97-structure): e3 + expert heads ----------------
__global__ __launch_bounds__(256)
void gemm_bt(const unsigned short* __restrict__ A0, int lda,
             const unsigned short* __restrict__ W0, int ldw,
             unsigned short* __restrict__ C0, int ldc,
             int K, const float* __restrict__ bias0, int elu,
             float* __restrict__ st, int Ntot,
             long eA, long eW, long eC, int eBias,
             const int* __restrict__ texp) {
  __shared__ __align__(16) unsigned short lA[128 * 64];
  __shared__ __align__(16) unsigned short lB[128 * 64];
  const int t = threadIdx.x;
  const int nx = gridDim.x, ny = gridDim.y;
  const int f = blockIdx.y * nx + blockIdx.x;
  const int xcd = f & 7, g = f >> 3;
  const int gdiv = g / nx;
  const int mt = xcd * (ny >> 3) + gdiv;
  const int nt = g - gdiv * nx;
  const int mBase = mt * 128;
  const int nBase = nt * 128;
  int e = texp ? texp[mt] : (int)blockIdx.z;
  if (e < 0) return;  // pad tile, uniform exit
  const unsigned short* A = A0 + (size_t)e * eA;
  const unsigned short* W = W0 + (size_t)e * eW;
  unsigned short* C = C0 + (size_t)e * eC;
  const float* bias = bias0 ? (bias0 + (size_t)e * eBias) : nullptr;
  const unsigned short* Ap = A + (size_t)mBase * lda;
  const unsigned short* Wp = W + (size_t)nBase * ldw;
  const int w = t >> 6, l = t & 63;
  const int wr = (w >> 1) * 64, wc = (w & 1) * 64;
  const int lm = l & 15, lg = l >> 4;

  f32x4 acc[4][4];
#pragma unroll
  for (int i = 0; i < 4; ++i)
#pragma unroll
    for (int j = 0; j < 4; ++j) {
      f32x4 z4 = {0.f, 0.f, 0.f, 0.f};
      acc[i][j] = z4;
    }

  for (int k0 = 0; k0 < K; k0 += 64) {
    __syncthreads();
#pragma unroll
    for (int it = 0; it < 4; ++it) {
      int chunk = it * 256 + t;
      int row = chunk >> 3, sc = chunk & 7;
      int gc = (sc ^ (row & 7)) << 3;  // swizzled source chunk (element offset)
      gl16(Ap + (size_t)row * lda + k0 + gc, &lA[chunk * 8]);
      gl16(Wp + (size_t)row * ldw + k0 + gc, &lB[chunk * 8]);
    }
    __syncthreads();
#pragma unroll
    for (int kk = 0; kk < 64; kk += 32) {
      short8 af[4], bfr[4];
#pragma unroll
      for (int i = 0; i < 4; ++i) {
        int ar = wr + i * 16 + lm;
        int ac = (kk >> 3) + lg;
        af[i] = *(const short8*)&lA[ar * 64 + ((ac ^ (ar & 7)) << 3)];
      }
#pragma unroll
      for (int j = 0; j < 4; ++j) {
        int br = wc + j * 16 + lm;
        int bc = (kk >> 3) + lg;
        bfr[j] = *(const short8*)&lB[br * 64 + ((bc ^ (br & 7)) << 3)];
      }
#pragma unroll
      for (int i = 0; i < 4; ++i)
#pragma unroll
        for (int j = 0; j < 4; ++j)
          acc[i][j] = __builtin_amdgcn_mfma_f32_16x16x32_bf16(af[i], bfr[j], acc[i][j], 0, 0, 0);
    }
  }

  // epilogue: D row = (lane>>4)*4 + reg, col = lane&15
#pragma unroll
  for (int j = 0; j < 4; ++j) {
    int n = nBase + wc + j * 16 + lm;
    float bj = bias ? bias[n] : 0.f;
    float s = 0.f, q = 0.f;
#pragma unroll
    for (int i = 0; i < 4; ++i) {
      int m0 = mBase + wr + i * 16 + lg * 4;
#pragma unroll
      for (int r = 0; r < 4; ++r) {
        float v = acc[i][j][r] + bj;
        if (elu) v = v > 0.f ? v : expm1f(v);
        s += v; q += v * v;
        C[(size_t)(m0 + r) * ldc + n] = f2bf(v);
      }
    }
    if (st) {
      s += __shfl_xor(s, 16, 64); s += __shfl_xor(s, 32, 64);
      q += __shfl_xor(q, 16, 64); q += __shfl_xor(q, 32, 64);
      if (lg == 0) { atomicAdd(&st[n], s); atomicAdd(&st[Ntot + n], q); }
    }
  }
}

// ---------------- in-place BN + ELU on bf16 [B,N], 8 elems/thread (N pow2)
__global__ void bn_apply(unsigned short* __restrict__ Y, const float* __restrict__ st,
                         const float* __restrict__ gam, const float* __restrict__ bet,
                         int N, float invB) {
  size_t i = (size_t)blockIdx.x * blockDim.x + threadIdx.x;
  size_t base = i * 8;
  int col = (int)(base & (size_t)(N - 1));
  float a8[8], b8[8];
#pragma unroll
  for (int k = 0; k < 8; ++k) {
    int c = col + k;
    float m = st[c] * invB;
    float var = st[N + c] * invB - m * m;
    float av = gam[c] * rsqrtf(var + 1e-5f);
    a8[k] = av;
    b8[k] = bet[c] - m * av;
  }
  uint4 u = *(uint4*)&Y[base];
  unsigned int uu[4] = {u.x, u.y, u.z, u.w};
  unsigned int oo[4];
#pragma unroll
  for (int k = 0; k < 4; ++k) {
    float vlo = bf2f(uu[k] & 0xFFFFu);
    float vhi = bf2f(uu[k] >> 16);
    float flo = a8[2 * k] * vlo + b8[2 * k];
    float fhi = a8[2 * k + 1] * vhi + b8[2 * k + 1];
    flo = flo > 0.f ? flo : expm1f(flo);
    fhi = fhi > 0.f ? fhi : expm1f(fhi);
    oo[k] = (unsigned int)f2bf(flo) | ((unsigned int)f2bf(fhi) << 16);
  }
  uint4 o = {oo[0], oo[1], oo[2], oo[3]};
  *(uint4*)&Y[base] = o;
}

// ---------------- cast ALL weights fp32->bf16 in one launch
__global__ void cast_all(const float* __restrict__ e1, const float* __restrict__ e2,
                         const float* __restrict__ e3, const float* __restrict__ s1,
                         const float* __restrict__ s2, const float* __restrict__ h1,
                         const float* __restrict__ h2, unsigned short* __restrict__ dst) {
  int i4 = blockIdx.x * 256 + threadIdx.x;
  const float* src;
  int rel;
  if (i4 < 786432) {
    if (i4 < 262144) { src = e1; rel = i4; }
    else             { src = e2; rel = i4 - 262144; }
  } else if (i4 < 1146880) {
    if (i4 < 819200) { src = e3; rel = i4 - 786432; }
    else             { src = s1; rel = i4 - 819200; }
  } else if (i4 < 2064384) {
    if (i4 < 1671168) { src = s2; rel = i4 - 1146880; }
    else              { src = h1; rel = i4 - 1671168; }
  } else { src = h2; rel = i4 - 2064384; }
  float4 v = ((const float4*)src)[rel];
  ushort4 o = {f2bf(v.x), f2bf(v.y), f2bf(v.z), f2bf(v.w)};
  ((ushort4*)dst)[i4] = o;
}

// ---------------- cast x [B,512] fp32 into z[:,128:640] bf16 (ld 640)
__global__ void cast_x(const float* __restrict__ x, unsigned short* __restrict__ z) {
  int i = blockIdx.x * blockDim.x + threadIdx.x;  // over B*128
  int b = i >> 7;
  int c = (i & 127) << 2;
  float4 v = *(const float4*)&x[(size_t)b * 512 + c];
  ushort4 o = {f2bf(v.x), f2bf(v.y), f2bf(v.z), f2bf(v.w)};
  *(ushort4*)&z[(size_t)b * 640 + 128 + c] = o;
}

// ---------------- sort step 1: per-block expert counts via wave ballots (NO atomics)
__global__ void hist_blocks(const int* __restrict__ gidx, int* __restrict__ bcnt) {
  int blk = blockIdx.x;
  int i = blk * 256 + threadIdx.x;
  int e = gidx[i];
  int l = threadIdx.x & 63, w = threadIdx.x >> 6;
  __shared__ int wc[4][3];
  unsigned long long m0 = __ballot(e == 0);
  unsigned long long m1 = __ballot(e == 1);
  unsigned long long m2 = __ballot(e == 2);
  if (l == 0) { wc[w][0] = __popcll(m0); wc[w][1] = __popcll(m1); wc[w][2] = __popcll(m2); }
  __syncthreads();
  if (threadIdx.x < 3)
    bcnt[blk * 3 + threadIdx.x] = wc[0][threadIdx.x] + wc[1][threadIdx.x] +
                                  wc[2][threadIdx.x] + wc[3][threadIdx.x];
}

// ---------------- sort step 2: one block; segment starts, vend, texp, and
// per-block exclusive offsets boff[blk][e]
__global__ void scan_plan(const int* __restrict__ bcnt, int* __restrict__ boff,
                          int* __restrict__ vend, int* __restrict__ texp) {
  __shared__ int sp[4];
  __shared__ int cnt[3];
  int t = threadIdx.x;
  if (t < 3) {
    int s = 0;
    for (int b = 0; b < NBLK; ++b) s += bcnt[b * 3 + t];
    cnt[t] = s;
  }
  __syncthreads();
  if (t == 0) {
    int p = 0;
    for (int e = 0; e < 3; ++e) {
      sp[e] = p; vend[e] = p + cnt[e];
      p += ((cnt[e] + 127) >> 7) << 7;
    }
    sp[3] = p;
  }
  __syncthreads();
  if (t < 3) {
    int run = sp[t];
    for (int b = 0; b < NBLK; ++b) { boff[b * 3 + t] = run; run += bcnt[b * 3 + t]; }
  }
  if (t < MT_H) {
    int r0 = t << 7, e = -1;
    for (int k = 0; k < 3; ++k)
      if (r0 >= sp[k] && r0 < sp[k + 1]) e = k;
    texp[t] = e;
  }
}

// ---------------- sort step 3: scatter via ballot-rank (NO atomics, stable)
__global__ void scatter2(const int* __restrict__ gidx, const int* __restrict__ boff,
                         int* __restrict__ perm) {
  int blk = blockIdx.x;
  int i = blk * 256 + threadIdx.x;
  int e = gidx[i];
  int l = threadIdx.x & 63, w = threadIdx.x >> 6;
  __shared__ int wc[4][3];
  unsigned long long m0 = __ballot(e == 0);
  unsigned long long m1 = __ballot(e == 1);
  unsigned long long m2 = __ballot(e == 2);
  if (l == 0) { wc[w][0] = __popcll(m0); wc[w][1] = __popcll(m1); wc[w][2] = __popcll(m2); }
  __syncthreads();
  unsigned long long me = (e == 0) ? m0 : ((e == 1) ? m1 : m2);
  int rank = __popcll(me & ((1ull << l) - 1ull));
  int woff = 0;
  for (int ww = 0; ww < w; ++ww) woff += wc[ww][e];
  perm[boff[blk * 3 + e] + woff + rank] = i;
}

// ---------------- gather + FUSED BN+ELU (s2 output): raw hidden -> bn -> ht
__global__ void gather_bn(const unsigned short* __restrict__ hid, const int* __restrict__ perm,
                          const int* __restrict__ texp, const int* __restrict__ vend,
                          const float* __restrict__ st, const float* __restrict__ gam,
                          const float* __restrict__ bet, float invB,
                          unsigned short* __restrict__ ht) {
  int idx = blockIdx.x * 256 + threadIdx.x;  // over MT_H*128*128
  int p = idx >> 7, c8 = (idx & 127) << 3;   // 8 cols of 1024 per thread
  int e = texp[p >> 7];
  uint4 o = {0u, 0u, 0u, 0u};
  if (e >= 0 && p < vend[e]) {
    float a8[8], b8[8];
#pragma unroll
    for (int k = 0; k < 8; ++k) {
      int c = c8 + k;
      float m = st[c] * invB;
      float var = st[1024 + c] * invB - m * m;
      float av = gam[c] * rsqrtf(var + 1e-5f);
      a8[k] = av;
      b8[k] = bet[c] - m * av;
    }
    int src = perm[p];
    uint4 u = *(const uint4*)&hid[(size_t)src * 1024 + c8];
    unsigned int uu[4] = {u.x, u.y, u.z, u.w};
    unsigned int oo[4];
#pragma unroll
    for (int k = 0; k < 4; ++k) {
      float vlo = bf2f(uu[k] & 0xFFFFu);
      float vhi = bf2f(uu[k] >> 16);
      float flo = a8[2 * k] * vlo + b8[2 * k];
      float fhi = a8[2 * k + 1] * vhi + b8[2 * k + 1];
      flo = flo > 0.f ? flo : expm1f(flo);
      fhi = fhi > 0.f ? fhi : expm1f(fhi);
      oo[k] = (unsigned int)f2bf(flo) | ((unsigned int)f2bf(fhi) << 16);
    }
    o.x = oo[0]; o.y = oo[1]; o.z = oo[2]; o.w = oo[3];
  }
  *(uint4*)&ht[(size_t)p * 1024 + c8] = o;
}

// ---------------- final: per sorted row p, dot(t2p[p,:], w3[e]) + b3[e], softplus
__global__ void final_pred(const unsigned short* __restrict__ t2, const int* __restrict__ perm,
                           const int* __restrict__ texp, const int* __restrict__ vend,
                           const float* __restrict__ w3, const float* __restrict__ b3,
                           float* __restrict__ out) {
  int p = blockIdx.x * 4 + (threadIdx.x >> 6);
  int l = threadIdx.x & 63;
  int e = texp[p >> 7];
  if (e < 0 || p >= vend[e]) return;
  ushort4 u = *(const ushort4*)&t2[(size_t)p * 256 + l * 4];
  float4 wv = *(const float4*)&w3[e * 256 + l * 4];
  float sum = bf2f(u.x) * wv.x + bf2f(u.y) * wv.y + bf2f(u.z) * wv.z + bf2f(u.w) * wv.w;
#pragma unroll
  for (int off = 32; off; off >>= 1) sum += __shfl_down(sum, off, 64);
  if (l == 0) {
    int orig = perm[p];
    float xr = sum + b3[e];
    float sp = (xr > 0.f) ? (xr + log1pf(expf(-xr))) : log1pf(expf(xr));
    float pl = -sp;
    out[orig] = pl;
    out[B_ + orig] = expf(pl * LN10_);
  }
}

extern "C" void kernel_launch(void* const* d_in, const int* in_sizes, int n_in,
                              void* d_out, int out_size, void* d_ws, size_t ws_size,
                              hipStream_t stream) {
  const float* x    = (const float*)d_in[0];
  const int*   gidx = (const int*)d_in[1];
  const float* e_w1 = (const float*)d_in[2];
  const float* e_g1 = (const float*)d_in[4];
  const float* e_be1= (const float*)d_in[5];
  const float* e_w2 = (const float*)d_in[6];
  const float* e_g2 = (const float*)d_in[8];
  const float* e_be2= (const float*)d_in[9];
  const float* e_w3 = (const float*)d_in[10];
  const float* e_b3 = (const float*)d_in[11];
  const float* s_w1 = (const float*)d_in[12];
  const float* s_g1 = (const float*)d_in[14];
  const float* s_be1= (const float*)d_in[15];
  const float* s_w2 = (const float*)d_in[16];
  const float* s_g2 = (const float*)d_in[18];
  const float* s_be2= (const float*)d_in[19];
  const float* h_w1 = (const float*)d_in[20];
  const float* h_b1 = (const float*)d_in[21];
  const float* h_w2 = (const float*)d_in[22];
  const float* h_b2 = (const float*)d_in[23];
  const float* h_w3 = (const float*)d_in[24];
  const float* h_b3 = (const float*)d_in[25];
  float* out = (float*)d_out;

  char* ws = (char*)d_ws;
  size_t off = 0;
  auto alloc = [&](size_t bytes) -> char* {
    char* p = ws + off;
    off += (bytes + 255) & ~(size_t)255;
    return p;
  };
  // bf16 weight buffers MUST stay contiguous & in this order (cast_all table)
  unsigned short* wb_e1 = (unsigned short*)alloc((size_t)2048 * 512 * 2);
  unsigned short* wb_e2 = (unsigned short*)alloc((size_t)1024 * 2048 * 2);
  unsigned short* wb_e3 = (unsigned short*)alloc((size_t)128 * 1024 * 2);
  unsigned short* wb_s1 = (unsigned short*)alloc((size_t)2048 * 640 * 2);
  unsigned short* wb_s2 = (unsigned short*)alloc((size_t)1024 * 2048 * 2);
  unsigned short* wb_h1 = (unsigned short*)alloc((size_t)3 * 512 * 1024 * 2);
  unsigned short* wb_h2 = (unsigned short*)alloc((size_t)3 * 256 * 512 * 2);
  unsigned short* z     = (unsigned short*)alloc((size_t)B_ * 640 * 2);
  unsigned short* bufA  = (unsigned short*)alloc((size_t)B_ * 2048 * 2);
  unsigned short* bufB  = (unsigned short*)alloc((size_t)B_ * 1024 * 2);
  // BN stats (memset each call)
  float* st = (float*)alloc(12288 * sizeof(float));
  float* st0 = st;            // e1: 2*2048
  float* st1 = st + 4096;     // e2: 2*1024
  float* st2 = st + 6144;     // s1: 2*2048
  float* st3 = st + 10240;    // s2: 2*1024
  // sort plan (all written before read each call; no memset needed)
  int* bcnt = (int*)alloc(NBLK * 3 * sizeof(int));
  int* boff = (int*)alloc(NBLK * 3 * sizeof(int));
  int* vend = (int*)alloc(3 * sizeof(int));
  int* texp = (int*)alloc(MT_H * sizeof(int));
  int* perm = (int*)alloc((size_t)MT_H * 128 * sizeof(int));
  // head buffers carved from dead regions:
  unsigned short* ht  = bufA;                                    // [MT_H*128,1024]
  unsigned short* t1p = bufA + (size_t)MT_H * 128 * 1024;        // [MT_H*128, 512]
  unsigned short* t2p = z;                                       // [MT_H*128, 256] (z dead then)

  cast_all<<<8448, 256, 0, stream>>>(e_w1, e_w2, e_w3, s_w1, s_w2, h_w1, h_w2, wb_e1);
  cast_x<<<(B_ * 128) / 256, 256, 0, stream>>>(x, z);
  hipMemsetAsync(st, 0, 12288 * sizeof(float), stream);
  // expert sort plan — deterministic, atomic-free
  hist_blocks<<<NBLK, 256, 0, stream>>>(gidx, bcnt);
  scan_plan<<<1, 512, 0, stream>>>(bcnt, boff, vend, texp);
  scatter2<<<NBLK, 256, 0, stream>>>(gidx, boff, perm);

  // encoder L1: [B,512] x [2048,512]^T -> bufA  (BN stats fused)
  gemm256<<<dim3(8, 128), 512, 0, stream>>>(z + 128, 640, wb_e1, 512, bufA, 2048, 512,
                                            st0, 2048);
  bn_apply<<<B_, 256, 0, stream>>>(bufA, st0, e_g1, e_be1, 2048, 1.0f / B_);
  // encoder L2: [B,2048] x [1024,2048]^T -> bufB
  gemm256<<<dim3(4, 128), 512, 0, stream>>>(bufA, 2048, wb_e2, 2048, bufB, 1024, 2048,
                                            st1, 1024);
  bn_apply<<<B_ / 2, 256, 0, stream>>>(bufB, st1, e_g2, e_be2, 1024, 1.0f / B_);
  // latent: [B,1024] x [128,1024]^T -> z[:,0:128] (ldc 640), +e_b3
  gemm_bt<<<dim3(1, 256), 256, 0, stream>>>(bufB, 1024, wb_e3, 1024, z, 640, 1024,
                                            e_b3, 0, nullptr, 0, 0, 0, 0, 0, nullptr);
  // shared L1: [B,640] x [2048,640]^T -> bufA
  gemm256<<<dim3(8, 128), 512, 0, stream>>>(z, 640, wb_s1, 640, bufA, 2048, 640,
                                            st2, 2048);
  bn_apply<<<B_, 256, 0, stream>>>(bufA, st2, s_g1, s_be1, 2048, 1.0f / B_);
  // shared L2: [B,2048] x [1024,2048]^T -> bufB (= RAW hidden pre-BN)
  gemm256<<<dim3(4, 128), 512, 0, stream>>>(bufA, 2048, wb_s2, 2048, bufB, 1024, 2048,
                                            st3, 1024);
  // NO bn_apply for s2: BN+ELU fused into gather_bn below.

  // gather RAW hidden -> BN+ELU -> expert-sorted ht (bufA dead after s2's A-read)
  gather_bn<<<(MT_H * 128 * 128) / 256, 256, 0, stream>>>(bufB, perm, texp, vend,
                                                          st3, s_g2, s_be2, 1.0f / B_, ht);

  // head L1, expert-sparse: t1p = elu(ht @ h_w1[e(mt)]^T + h_b1[e]) [Mp,512]
  gemm_bt<<<dim3(4, MT_H), 256, 0, stream>>>(ht, 1024, wb_h1, 1024, t1p, 512, 1024,
                                             h_b1, 1, nullptr, 0,
                                             0, (long)512 * 1024, 0, 512, texp);
  // head L2, expert-sparse: t2p = elu(t1p @ h_w2[e(mt)]^T + h_b2[e]) [Mp,256]
  gemm_bt<<<dim3(2, MT_H), 256, 0, stream>>>(t1p, 512, wb_h2, 512, t2p, 256, 512,
                                             h_b2, 1, nullptr, 0,
                                             0, (long)256 * 512, 0, 256, texp);

  final_pred<<<(MT_H * 128) / 4, 256, 0, stream>>>(t2p, perm, texp, vend, h_w3, h_b3, out);
}